// Round 25
// baseline (148.159 us; speedup 1.0000x reference)
//
#include <hip/hip_runtime.h>

#define NS 10000
#define DD 64
#define HH 128
#define EE 50000
#define SLOPE 0.01f
#define BPAD 8448      // B^T row length in c (8192 w2 + 64 b2 + 192 zero)

typedef __attribute__((ext_vector_type(8))) short short8;
typedef __attribute__((ext_vector_type(8))) _Float16 half8;
typedef __attribute__((ext_vector_type(4))) float f32x4;

static __device__ __forceinline__ unsigned short f2bf(float f) {
  unsigned int u = __float_as_uint(f);
  u += 0x7fff + ((u >> 16) & 1);   // round-to-nearest-even
  return (unsigned short)(u >> 16);
}
static __device__ __forceinline__ unsigned short f2h(float f) {
  _Float16 v = (_Float16)f;
  return __builtin_bit_cast(unsigned short, v);
}
static __device__ __forceinline__ unsigned pkmul(unsigned a, unsigned b) {
  unsigned r;
  asm("v_pk_mul_f16 %0, %1, %2" : "=v"(r) : "v"(a), "v"(b));
  return r;
}
static __device__ __forceinline__ unsigned duplo(unsigned v) {
  v &= 0xffffu; return v | (v << 16);
}
static __device__ __forceinline__ unsigned duphi(unsigned v) {
  v >>= 16; return v | (v << 16);
}

__device__ __forceinline__ float wave_sum64(float v) {
  #pragma unroll
  for (int m = 32; m >= 1; m >>= 1) v += __shfl_xor(v, m, 64);
  return v;
}

// k_prep: [0,128): w2 64x64 LDS transpose -> w2e rows (fp16, stride BPAD).
//         [128]: b2 rows + zero pad of w2e.
//         [129, 129+2500): LN -> h (f32) / h16 (fp16), cntdst.
//         [2629, 2629+782): u-GEMM (inline ea cast + w1 LDS transpose) -> u16.
// agg|cntdst zeroed by a prior memset (r13 race lesson).
#define TBLK 128
#define PBLK 2500
#define UB 782
__global__ __launch_bounds__(256) void k_prep(const float* __restrict__ x,
    const float* __restrict__ gamma, const float* __restrict__ beta,
    float* __restrict__ h, unsigned short* __restrict__ h16,
    const float* __restrict__ ea, const float* __restrict__ w2,
    unsigned short* __restrict__ w2e, const float* __restrict__ w1,
    const float* __restrict__ b1, unsigned short* __restrict__ u16,
    const float* __restrict__ b2, const int* __restrict__ ei,
    int* __restrict__ cntdst) {
  __shared__ __align__(16) unsigned char smem[18432];
  int t = threadIdx.x;
  int bid = blockIdx.x;
  if (bid < TBLK) {
    float (*tile)[65] = (float(*)[65])smem;   // 16640 B
    int k = bid;
    #pragma unroll
    for (int i = 0; i < 16; ++i) {
      int idx = t + i * 256;          // d*64+f
      tile[idx >> 6][idx & 63] = w2[k * (DD * DD) + idx];
    }
    __syncthreads();
    #pragma unroll
    for (int it = 0; it < 2; ++it) {
      int slot = t + it * 256;        // 0..511
      int f = slot >> 3, l8 = slot & 7;
      short8 o;
      #pragma unroll
      for (int j = 0; j < 8; ++j) o[j] = f2h(tile[l8 * 8 + j][f]);
      *(short8*)(w2e + (size_t)f * BPAD + k * DD + l8 * 8) = o;
    }
    return;
  }
  if (bid == TBLK) {
    // b2 rows: w2e[f][8192+d] = fp16(b2[d*64+f])
    #pragma unroll
    for (int i = 0; i < 16; ++i) {
      int idx = t + i * 256;          // d*64+f
      int d = idx >> 6, f = idx & 63;
      w2e[(size_t)f * BPAD + 8192 + d] = f2h(b2[idx]);
    }
    // zero pad: c in [8256, 8448)
    #pragma unroll
    for (int i = 0; i < 6; ++i) {
      int slot = t + i * 256;         // 0..1535
      int f = slot / 24, z8 = slot % 24;
      short8 z = {};
      *(short8*)(w2e + (size_t)f * BPAD + 8256 + z8 * 8) = z;
    }
    return;
  }
  if (bid < TBLK + 1 + PBLK) {
    int pbid = bid - TBLK - 1;
    int gid = pbid * 256 + t;
    if (gid < EE) atomicAdd(&cntdst[ei[EE + gid]], 1);
    int wid = t >> 6;
    int lane = t & 63;
    int row = pbid * 4 + wid;
    if (row >= NS) return;
    float v = x[row * DD + lane];
    float s = wave_sum64(v);
    float s2 = wave_sum64(v * v);
    float mu = s * (1.0f / 64.0f);
    float var = s2 * (1.0f / 64.0f) - mu * mu;
    float r = rsqrtf(var + 1e-5f);
    float hn = (v - mu) * r * gamma[lane] + beta[lane];
    float hv = hn >= 0.f ? hn : SLOPE * hn;
    h[row * DD + lane] = hv;
    h16[row * DD + lane] = f2h(hv);
    return;
  }
  // u-GEMM: 64 edge-rows per block, inline ea cast, w1 via LDS transpose.
  int ublk = bid - TBLK - 1 - PBLK;
  unsigned short (*W)[72] = (unsigned short(*)[72])smem;   // 128x72 shorts
  int w = t >> 6, lane = t & 63, lr = lane & 15, lg = lane >> 4;
  int r0 = ublk * 64 + w * 16;
  int ra = r0 + lr; if (ra >= EE) ra = EE - 1;
  const float* ep = ea + (size_t)ra * DD;
  float4 e0 = *(const float4*)(ep + lg * 8);
  float4 e1 = *(const float4*)(ep + lg * 8 + 4);
  float4 e2 = *(const float4*)(ep + 32 + lg * 8);
  float4 e3 = *(const float4*)(ep + 32 + lg * 8 + 4);
  #pragma unroll
  for (int i = 0; i < 32; ++i) {
    int idx = t + i * 256;            // idx = d*128 + hc
    int d = idx >> 7, hc = idx & 127;
    W[hc][d] = f2bf(w1[idx]);
  }
  __syncthreads();
  short8 a0, a1;
  a0[0] = f2bf(e0.x); a0[1] = f2bf(e0.y); a0[2] = f2bf(e0.z); a0[3] = f2bf(e0.w);
  a0[4] = f2bf(e1.x); a0[5] = f2bf(e1.y); a0[6] = f2bf(e1.z); a0[7] = f2bf(e1.w);
  a1[0] = f2bf(e2.x); a1[1] = f2bf(e2.y); a1[2] = f2bf(e2.z); a1[3] = f2bf(e2.w);
  a1[4] = f2bf(e3.x); a1[5] = f2bf(e3.y); a1[6] = f2bf(e3.z); a1[7] = f2bf(e3.w);
  short8 bb0[8], bb1[8];
  #pragma unroll
  for (int ni = 0; ni < 8; ++ni) {
    bb0[ni] = *(const short8*)(&W[ni * 16 + lr][lg * 8]);
    bb1[ni] = *(const short8*)(&W[ni * 16 + lr][32 + lg * 8]);
  }
  f32x4 acc[8] = {};
  #pragma unroll
  for (int ni = 0; ni < 8; ++ni) {
    acc[ni] = __builtin_amdgcn_mfma_f32_16x16x32_bf16(a0, bb0[ni], acc[ni], 0, 0, 0);
    acc[ni] = __builtin_amdgcn_mfma_f32_16x16x32_bf16(a1, bb1[ni], acc[ni], 0, 0, 0);
  }
  #pragma unroll
  for (int ni = 0; ni < 8; ++ni) {
    int col = ni * 16 + lr;
    float bb = b1[col];
    #pragma unroll
    for (int reg = 0; reg < 4; ++reg) {
      int gr = r0 + lg * 4 + reg;
      if (gr < EE) {
        float vv = acc[ni][reg] + bb;
        u16[(size_t)gr * HH + col] = f2h(vv >= 0.f ? vv : SLOPE * vv);
      }
    }
  }
}

// Direct message GEMM (T-free), fp16 packed A-build, c-split 4-way,
// double-buffered 128-col sub-chunks, M=4 tiles per wave (64 edges):
// each B-fragment LDS read feeds 4 MFMAs -> LDS-read traffic halved vs M=2.
__global__ __launch_bounds__(256) void k_msgd(
    const unsigned short* __restrict__ u16, const unsigned short* __restrict__ h16,
    const unsigned short* __restrict__ w2e, const int* __restrict__ ei,
    float* __restrict__ agg) {
  __shared__ unsigned short Bs[2][64 * 128];   // 2 x 16 KB, swizzled
  int t = threadIdx.x;
  int w = t >> 6, lane = t & 63, lr = lane & 15, lg = lane >> 4;
  int cq = blockIdx.y;                 // 0..3; owns 128-col sub-chunks [cq*16, +16)
  int ebase = (blockIdx.x * 4 + w) * 64;
  int ec[4], sc[4];
  #pragma unroll
  for (int m = 0; m < 4; ++m) {
    int e = ebase + m * 16 + lr;
    ec[m] = e < EE ? e : EE - 1;
    sc[m] = ei[ec[m]];
  }
  // h pairs, packed fp16: hp[m][par][jj]
  unsigned hp[4][2][4];
  #pragma unroll
  for (int m = 0; m < 4; ++m)
    #pragma unroll
    for (int par = 0; par < 2; ++par) {
      uint4 v = *(const uint4*)(h16 + (size_t)sc[m] * DD + par * 32 + lg * 8);
      hp[m][par][0] = v.x; hp[m][par][1] = v.y;
      hp[m][par][2] = v.z; hp[m][par][3] = v.w;
    }
  // hoisted u: 32 fp16 per edge (k in [cq*32, +32)); dword ci = sub-chunk ci
  union U16x { uint4 q[4]; unsigned s[16]; };
  U16x ub[4];
  #pragma unroll
  for (int m = 0; m < 4; ++m) {
    const unsigned short* p = u16 + (size_t)ec[m] * HH + cq * 32;
    #pragma unroll
    for (int i = 0; i < 4; ++i) ub[m].q[i] = *(const uint4*)(p + i * 8);
  }
  short8 sreg[4];
  auto issue = [&](int ch) {
    #pragma unroll
    for (int i = 0; i < 4; ++i) {
      int slot = t + i * 256;
      int f = slot >> 4, o8 = slot & 15;
      sreg[i] = *(const short8*)(w2e + (size_t)f * BPAD + ch * 128 + o8 * 8);
    }
  };
  auto wrbuf = [&](int b) {
    #pragma unroll
    for (int i = 0; i < 4; ++i) {
      int slot = t + i * 256;
      int f = slot >> 4, o8 = slot & 15;
      *(short8*)(&Bs[b][f * 128 + (o8 ^ (f & 7)) * 8]) = sreg[i];
    }
  };
  f32x4 acc[4][4] = {};   // [m][ft]
  auto mfma_block = [&](int cur, const unsigned* ulo, const unsigned* uhi) {
    #pragma unroll
    for (int ks = 0; ks < 4; ++ks) {
      int par = ks & 1, kk = ks >> 1;
      union { unsigned u[4]; half8 h; } pa[4];
      #pragma unroll
      for (int m = 0; m < 4; ++m) {
        unsigned sv = kk ? uhi[m] : ulo[m];
        #pragma unroll
        for (int jj = 0; jj < 4; ++jj)
          pa[m].u[jj] = pkmul(sv, hp[m][par][jj]);
      }
      int o8r = ks * 4 + lg;
      #pragma unroll
      for (int ft = 0; ft < 4; ++ft) {
        int f = ft * 16 + lr;
        half8 b = *(const half8*)(&Bs[cur][f * 128 + ((o8r ^ (f & 7))) * 8]);
        #pragma unroll
        for (int m = 0; m < 4; ++m)
          acc[m][ft] = __builtin_amdgcn_mfma_f32_16x16x32_f16(pa[m].h, b,
                                                              acc[m][ft], 0, 0, 0);
      }
    }
  };
  // prologue: buf0 <- sub-chunk 0; sreg <- sub-chunk 1
  issue(cq * 16 + 0);
  wrbuf(0);
  issue(cq * 16 + 1);
  __syncthreads();
  #pragma unroll
  for (int ci = 0; ci < 16; ++ci) {
    int cur = ci & 1;
    if (ci < 15) wrbuf(cur ^ 1);                 // data for ci+1
    else if (cq == 3) wrbuf(cur ^ 1);            // bias sub-chunk data
    if (ci < 14) issue(cq * 16 + ci + 2);        // loads fly under MFMA
    else if (ci == 14 && cq == 3) issue(64);     // bias sub-chunk (c 8192..8320)
    unsigned ulo[4], uhi[4];
    #pragma unroll
    for (int m = 0; m < 4; ++m) {
      unsigned uw = ub[m].s[ci];                 // static index (rule #20)
      ulo[m] = duplo(uw); uhi[m] = duphi(uw);
    }
    mfma_block(cur, ulo, uhi);
    __syncthreads();
  }
  if (cq == 3) {
    // bias sub-chunk in buf[0] (16 & 1 == 0): u = (1.0h, 0)
    unsigned ulo[4] = {0x3C003C00u, 0x3C003C00u, 0x3C003C00u, 0x3C003C00u};
    unsigned uhi[4] = {0u, 0u, 0u, 0u};
    mfma_block(0, ulo, uhi);
  }
  #pragma unroll
  for (int m = 0; m < 4; ++m)
    #pragma unroll
    for (int reg = 0; reg < 4; ++reg) {
      int ee = ebase + m * 16 + lg * 4 + reg;
      if (ee < EE) {
        int dstn = ei[EE + ee];
        #pragma unroll
        for (int ft = 0; ft < 4; ++ft)
          atomicAdd(&agg[(size_t)dstn * DD + ft * 16 + lr], acc[m][ft][reg]);
      }
    }
}

// out = x + agg/max(cnt,1) + h@root + bias
__global__ __launch_bounds__(256) void k_final(const float* __restrict__ x,
    const float* __restrict__ h, const float* __restrict__ root,
    const float* __restrict__ bias, const float* __restrict__ agg,
    const int* __restrict__ cnt, float* __restrict__ out) {
  __shared__ float Bs[DD][DD + 1];
  __shared__ float As[32][DD];
  int t = threadIdx.x;
  #pragma unroll
  for (int i = 0; i < 16; ++i) {
    int idx = t + i * 256;
    Bs[idx >> 6][idx & 63] = root[idx];
  }
  int row0 = blockIdx.x * 32;
  #pragma unroll
  for (int i = 0; i < 8; ++i) {
    int idx = t + i * 256;
    int r = idx >> 6, d = idx & 63;
    int gr = row0 + r;
    As[r][d] = (gr < NS) ? h[gr * DD + d] : 0.f;
  }
  __syncthreads();
  int r = t >> 3;
  int c0 = (t & 7) * 8;
  int gr = row0 + r;
  if (gr >= NS) return;
  float acc[8] = {};
  for (int d = 0; d < DD; ++d) {
    float a = As[r][d];
    #pragma unroll
    for (int j = 0; j < 8; ++j) acc[j] += a * Bs[d][c0 + j];
  }
  float inv = 1.0f / fmaxf((float)cnt[gr], 1.0f);
  #pragma unroll
  for (int j = 0; j < 8; ++j) {
    size_t gi = (size_t)gr * DD + c0 + j;
    out[gi] = x[gi] + agg[gi] * inv + acc[j] + bias[c0 + j];
  }
}

extern "C" void kernel_launch(void* const* d_in, const int* in_sizes, int n_in,
                              void* d_out, int out_size, void* d_ws, size_t ws_size,
                              hipStream_t stream) {
  const float* x     = (const float*)d_in[0];
  const float* ea    = (const float*)d_in[1];
  const float* gamma = (const float*)d_in[2];
  const float* beta  = (const float*)d_in[3];
  const float* w1    = (const float*)d_in[4];
  const float* b1    = (const float*)d_in[5];
  const float* w2    = (const float*)d_in[6];
  const float* b2    = (const float*)d_in[7];
  const float* root  = (const float*)d_in[8];
  const float* bias  = (const float*)d_in[9];
  const int*   ei    = (const int*)d_in[10];
  float* out = (float*)d_out;

  char* p = (char*)d_ws;
  auto carve = [&](size_t bytes) {
    char* q = p;
    p += (bytes + 255) & ~(size_t)255;
    return q;
  };
  float* h            = (float*)carve(sizeof(float) * NS * DD);
  unsigned short* h16 = (unsigned short*)carve(sizeof(short) * NS * DD);
  unsigned short* w2e = (unsigned short*)carve(sizeof(short) * (size_t)DD * BPAD);
  unsigned short* u16 = (unsigned short*)carve(sizeof(short) * (size_t)EE * HH);
  // contiguous zero-region: agg | cntdst (memset BEFORE k_prep — r13 lesson)
  char* z0 = p;
  float* agg          = (float*)carve(sizeof(float) * NS * DD);
  int* cntdst         = (int*)carve(sizeof(int) * NS);
  size_t zlen = (size_t)(p - z0);

  (void)hipMemsetAsync(z0, 0, zlen, stream);
  k_prep<<<dim3(TBLK + 1 + PBLK + UB), dim3(256), 0, stream>>>(
      x, gamma, beta, h, h16, ea, w2, w2e, w1, b1, u16, b2, ei, cntdst);
  k_msgd<<<dim3((EE + 255) / 256, 4), dim3(256), 0, stream>>>(
      u16, h16, w2e, ei, agg);
  k_final<<<dim3((NS + 31) / 32), dim3(256), 0, stream>>>(x, h, root, bias, agg,
                                                          cntdst, out);
}

// Round 26
// 113.815 us; speedup vs baseline: 1.3018x; 1.3018x over previous
//
#include <hip/hip_runtime.h>

#define NS 10000
#define DD 64
#define HH 128
#define EE 50000
#define SLOPE 0.01f
#define BPAD 8448      // B^T row length in c (8192 w2 + 64 b2 + 192 zero)

typedef __attribute__((ext_vector_type(8))) short short8;
typedef __attribute__((ext_vector_type(8))) _Float16 half8;
typedef __attribute__((ext_vector_type(4))) float f32x4;

static __device__ __forceinline__ unsigned short f2bf(float f) {
  unsigned int u = __float_as_uint(f);
  u += 0x7fff + ((u >> 16) & 1);   // round-to-nearest-even
  return (unsigned short)(u >> 16);
}
static __device__ __forceinline__ unsigned short f2h(float f) {
  _Float16 v = (_Float16)f;
  return __builtin_bit_cast(unsigned short, v);
}
static __device__ __forceinline__ unsigned pkmul(unsigned a, unsigned b) {
  unsigned r;
  asm("v_pk_mul_f16 %0, %1, %2" : "=v"(r) : "v"(a), "v"(b));
  return r;
}
static __device__ __forceinline__ unsigned duplo(unsigned v) {
  v &= 0xffffu; return v | (v << 16);
}
static __device__ __forceinline__ unsigned duphi(unsigned v) {
  v >>= 16; return v | (v << 16);
}

__device__ __forceinline__ float wave_sum64(float v) {
  #pragma unroll
  for (int m = 32; m >= 1; m >>= 1) v += __shfl_xor(v, m, 64);
  return v;
}

// k_prep: [0,128): w2 64x64 LDS transpose -> w2e rows (fp16, stride BPAD).
//         [128]: b2 rows + zero pad of w2e.
//         [129, 129+2500): LN -> h (f32) / h16 (fp16), cntdst.
//         [2629, 2629+782): u-GEMM (inline ea cast + w1 LDS transpose) -> u16.
// agg|cntdst zeroed by a prior memset (r13 race lesson).
#define TBLK 128
#define PBLK 2500
#define UB 782
__global__ __launch_bounds__(256) void k_prep(const float* __restrict__ x,
    const float* __restrict__ gamma, const float* __restrict__ beta,
    float* __restrict__ h, unsigned short* __restrict__ h16,
    const float* __restrict__ ea, const float* __restrict__ w2,
    unsigned short* __restrict__ w2e, const float* __restrict__ w1,
    const float* __restrict__ b1, unsigned short* __restrict__ u16,
    const float* __restrict__ b2, const int* __restrict__ ei,
    int* __restrict__ cntdst) {
  __shared__ __align__(16) unsigned char smem[18432];
  int t = threadIdx.x;
  int bid = blockIdx.x;
  if (bid < TBLK) {
    float (*tile)[65] = (float(*)[65])smem;   // 16640 B
    int k = bid;
    #pragma unroll
    for (int i = 0; i < 16; ++i) {
      int idx = t + i * 256;          // d*64+f
      tile[idx >> 6][idx & 63] = w2[k * (DD * DD) + idx];
    }
    __syncthreads();
    #pragma unroll
    for (int it = 0; it < 2; ++it) {
      int slot = t + it * 256;        // 0..511
      int f = slot >> 3, l8 = slot & 7;
      short8 o;
      #pragma unroll
      for (int j = 0; j < 8; ++j) o[j] = f2h(tile[l8 * 8 + j][f]);
      *(short8*)(w2e + (size_t)f * BPAD + k * DD + l8 * 8) = o;
    }
    return;
  }
  if (bid == TBLK) {
    // b2 rows: w2e[f][8192+d] = fp16(b2[d*64+f])
    #pragma unroll
    for (int i = 0; i < 16; ++i) {
      int idx = t + i * 256;          // d*64+f
      int d = idx >> 6, f = idx & 63;
      w2e[(size_t)f * BPAD + 8192 + d] = f2h(b2[idx]);
    }
    // zero pad: c in [8256, 8448)
    #pragma unroll
    for (int i = 0; i < 6; ++i) {
      int slot = t + i * 256;         // 0..1535
      int f = slot / 24, z8 = slot % 24;
      short8 z = {};
      *(short8*)(w2e + (size_t)f * BPAD + 8256 + z8 * 8) = z;
    }
    return;
  }
  if (bid < TBLK + 1 + PBLK) {
    int pbid = bid - TBLK - 1;
    int gid = pbid * 256 + t;
    if (gid < EE) atomicAdd(&cntdst[ei[EE + gid]], 1);
    int wid = t >> 6;
    int lane = t & 63;
    int row = pbid * 4 + wid;
    if (row >= NS) return;
    float v = x[row * DD + lane];
    float s = wave_sum64(v);
    float s2 = wave_sum64(v * v);
    float mu = s * (1.0f / 64.0f);
    float var = s2 * (1.0f / 64.0f) - mu * mu;
    float r = rsqrtf(var + 1e-5f);
    float hn = (v - mu) * r * gamma[lane] + beta[lane];
    float hv = hn >= 0.f ? hn : SLOPE * hn;
    h[row * DD + lane] = hv;
    h16[row * DD + lane] = f2h(hv);
    return;
  }
  // u-GEMM: 64 edge-rows per block, inline ea cast, w1 via LDS transpose.
  int ublk = bid - TBLK - 1 - PBLK;
  unsigned short (*W)[72] = (unsigned short(*)[72])smem;   // 128x72 shorts
  int w = t >> 6, lane = t & 63, lr = lane & 15, lg = lane >> 4;
  int r0 = ublk * 64 + w * 16;
  int ra = r0 + lr; if (ra >= EE) ra = EE - 1;
  const float* ep = ea + (size_t)ra * DD;
  float4 e0 = *(const float4*)(ep + lg * 8);
  float4 e1 = *(const float4*)(ep + lg * 8 + 4);
  float4 e2 = *(const float4*)(ep + 32 + lg * 8);
  float4 e3 = *(const float4*)(ep + 32 + lg * 8 + 4);
  #pragma unroll
  for (int i = 0; i < 32; ++i) {
    int idx = t + i * 256;            // idx = d*128 + hc
    int d = idx >> 7, hc = idx & 127;
    W[hc][d] = f2bf(w1[idx]);
  }
  __syncthreads();
  short8 a0, a1;
  a0[0] = f2bf(e0.x); a0[1] = f2bf(e0.y); a0[2] = f2bf(e0.z); a0[3] = f2bf(e0.w);
  a0[4] = f2bf(e1.x); a0[5] = f2bf(e1.y); a0[6] = f2bf(e1.z); a0[7] = f2bf(e1.w);
  a1[0] = f2bf(e2.x); a1[1] = f2bf(e2.y); a1[2] = f2bf(e2.z); a1[3] = f2bf(e2.w);
  a1[4] = f2bf(e3.x); a1[5] = f2bf(e3.y); a1[6] = f2bf(e3.z); a1[7] = f2bf(e3.w);
  short8 bb0[8], bb1[8];
  #pragma unroll
  for (int ni = 0; ni < 8; ++ni) {
    bb0[ni] = *(const short8*)(&W[ni * 16 + lr][lg * 8]);
    bb1[ni] = *(const short8*)(&W[ni * 16 + lr][32 + lg * 8]);
  }
  f32x4 acc[8] = {};
  #pragma unroll
  for (int ni = 0; ni < 8; ++ni) {
    acc[ni] = __builtin_amdgcn_mfma_f32_16x16x32_bf16(a0, bb0[ni], acc[ni], 0, 0, 0);
    acc[ni] = __builtin_amdgcn_mfma_f32_16x16x32_bf16(a1, bb1[ni], acc[ni], 0, 0, 0);
  }
  #pragma unroll
  for (int ni = 0; ni < 8; ++ni) {
    int col = ni * 16 + lr;
    float bb = b1[col];
    #pragma unroll
    for (int reg = 0; reg < 4; ++reg) {
      int gr = r0 + lg * 4 + reg;
      if (gr < EE) {
        float vv = acc[ni][reg] + bb;
        u16[(size_t)gr * HH + col] = f2h(vv >= 0.f ? vv : SLOPE * vv);
      }
    }
  }
}

// Direct message GEMM (T-free), fp16 A-build, c-split 4-way, M=2,
// 64-col sub-chunks double-buffered: LDS = 2 x 8 KB = 16 KB -> ~5 blocks/CU
// (2.5x the TLP of the 32 KB version). One k per sub-chunk (c = k*64+d).
__global__ __launch_bounds__(256) void k_msgd(
    const unsigned short* __restrict__ u16, const unsigned short* __restrict__ h16,
    const unsigned short* __restrict__ w2e, const int* __restrict__ ei,
    float* __restrict__ agg) {
  __shared__ unsigned short Bs[2][64 * 64];   // 2 x 8 KB, swizzled
  int t = threadIdx.x;
  int w = t >> 6, lane = t & 63, lr = lane & 15, lg = lane >> 4;
  int cq = blockIdx.y;                 // 0..3; owns 64-col sub-chunks [cq*32, +32)
  int base = cq * 32;
  int ebase = (blockIdx.x * 4 + w) * 32;
  int e0 = ebase + lr, e1 = ebase + 16 + lr;
  int e0c = e0 < EE ? e0 : EE - 1;
  int e1c = e1 < EE ? e1 : EE - 1;
  int s0 = ei[e0c], s1 = ei[e1c];
  // h pairs, packed fp16: hp[par][jj] = (h[2jj], h[2jj+1]) of d-slice par*32+lg*8
  unsigned hp0[2][4], hp1[2][4];
  #pragma unroll
  for (int par = 0; par < 2; ++par) {
    uint4 v0 = *(const uint4*)(h16 + (size_t)s0 * DD + par * 32 + lg * 8);
    uint4 v1 = *(const uint4*)(h16 + (size_t)s1 * DD + par * 32 + lg * 8);
    hp0[par][0] = v0.x; hp0[par][1] = v0.y; hp0[par][2] = v0.z; hp0[par][3] = v0.w;
    hp1[par][0] = v1.x; hp1[par][1] = v1.y; hp1[par][2] = v1.z; hp1[par][3] = v1.w;
  }
  // hoisted u: 32 fp16 (k in [cq*32, +32)); sub-chunk ci -> k = base+ci
  union { uint4 q[4]; unsigned s[16]; } ub0, ub1;
  {
    const unsigned short* p0 = u16 + (size_t)e0c * HH + cq * 32;
    const unsigned short* p1 = u16 + (size_t)e1c * HH + cq * 32;
    #pragma unroll
    for (int i = 0; i < 4; ++i) {
      ub0.q[i] = *(const uint4*)(p0 + i * 8);
      ub1.q[i] = *(const uint4*)(p1 + i * 8);
    }
  }
  short8 sreg[2];
  auto issue = [&](int sc) {   // sc = global 64-col sub-chunk; col base sc*64
    #pragma unroll
    for (int i = 0; i < 2; ++i) {
      int slot = t + i * 256;                  // 0..511
      int f = slot >> 3, o8 = slot & 7;
      sreg[i] = *(const short8*)(w2e + (size_t)f * BPAD + sc * 64 + o8 * 8);
    }
  };
  auto wrbuf = [&](int b) {
    #pragma unroll
    for (int i = 0; i < 2; ++i) {
      int slot = t + i * 256;
      int f = slot >> 3, o8 = slot & 7;
      *(short8*)(&Bs[b][f * 64 + (o8 ^ (f & 7)) * 8]) = sreg[i];
    }
  };
  f32x4 acc[2][4] = {};
  auto mfma_block = [&](int cur, unsigned d0, unsigned d1) {
    #pragma unroll
    for (int ks = 0; ks < 2; ++ks) {           // ks == par (d half)
      union { unsigned u[4]; half8 h; } pa0, pa1;
      #pragma unroll
      for (int jj = 0; jj < 4; ++jj) {
        pa0.u[jj] = pkmul(d0, hp0[ks][jj]);
        pa1.u[jj] = pkmul(d1, hp1[ks][jj]);
      }
      int o8r = ks * 4 + lg;                   // slot of (ks*32 + lg*8)
      #pragma unroll
      for (int ft = 0; ft < 4; ++ft) {
        int f = ft * 16 + lr;
        half8 b = *(const half8*)(&Bs[cur][f * 64 + ((o8r ^ (f & 7))) * 8]);
        acc[0][ft] = __builtin_amdgcn_mfma_f32_16x16x32_f16(pa0.h, b,
                                                            acc[0][ft], 0, 0, 0);
        acc[1][ft] = __builtin_amdgcn_mfma_f32_16x16x32_f16(pa1.h, b,
                                                            acc[1][ft], 0, 0, 0);
      }
    }
  };
  // prologue
  issue(base + 0);
  wrbuf(0);
  issue(base + 1);
  __syncthreads();
  #pragma unroll
  for (int ci = 0; ci < 32; ++ci) {
    int cur = ci & 1;
    if (ci < 31) wrbuf(cur ^ 1);               // data for ci+1
    else if (cq == 3) wrbuf(cur ^ 1);          // bias sub-chunk data
    if (ci < 30) issue(base + ci + 2);         // loads fly under MFMA
    else if (ci == 30 && cq == 3) issue(128);  // bias: cols 8192..8256
    unsigned uw = ub0.s[ci >> 1];              // static index (rule #20)
    unsigned vw = ub1.s[ci >> 1];
    unsigned d0 = (ci & 1) ? duphi(uw) : duplo(uw);
    unsigned d1 = (ci & 1) ? duphi(vw) : duplo(vw);
    mfma_block(cur, d0, d1);
    __syncthreads();
  }
  if (cq == 3) {
    // bias sub-chunk in buf[0] (32 & 1 == 0): u = 1.0h for all d
    mfma_block(0, 0x3C003C00u, 0x3C003C00u);
  }
  #pragma unroll
  for (int m = 0; m < 2; ++m)
    #pragma unroll
    for (int reg = 0; reg < 4; ++reg) {
      int ee = ebase + m * 16 + lg * 4 + reg;
      if (ee < EE) {
        int dstn = ei[EE + ee];
        #pragma unroll
        for (int ft = 0; ft < 4; ++ft)
          atomicAdd(&agg[(size_t)dstn * DD + ft * 16 + lr],
                    m == 0 ? acc[0][ft][reg] : acc[1][ft][reg]);
      }
    }
}

// out = x + agg/max(cnt,1) + h@root + bias
__global__ __launch_bounds__(256) void k_final(const float* __restrict__ x,
    const float* __restrict__ h, const float* __restrict__ root,
    const float* __restrict__ bias, const float* __restrict__ agg,
    const int* __restrict__ cnt, float* __restrict__ out) {
  __shared__ float Bs[DD][DD + 1];
  __shared__ float As[32][DD];
  int t = threadIdx.x;
  #pragma unroll
  for (int i = 0; i < 16; ++i) {
    int idx = t + i * 256;
    Bs[idx >> 6][idx & 63] = root[idx];
  }
  int row0 = blockIdx.x * 32;
  #pragma unroll
  for (int i = 0; i < 8; ++i) {
    int idx = t + i * 256;
    int r = idx >> 6, d = idx & 63;
    int gr = row0 + r;
    As[r][d] = (gr < NS) ? h[gr * DD + d] : 0.f;
  }
  __syncthreads();
  int r = t >> 3;
  int c0 = (t & 7) * 8;
  int gr = row0 + r;
  if (gr >= NS) return;
  float acc[8] = {};
  for (int d = 0; d < DD; ++d) {
    float a = As[r][d];
    #pragma unroll
    for (int j = 0; j < 8; ++j) acc[j] += a * Bs[d][c0 + j];
  }
  float inv = 1.0f / fmaxf((float)cnt[gr], 1.0f);
  #pragma unroll
  for (int j = 0; j < 8; ++j) {
    size_t gi = (size_t)gr * DD + c0 + j;
    out[gi] = x[gi] + agg[gi] * inv + acc[j] + bias[c0 + j];
  }
}

extern "C" void kernel_launch(void* const* d_in, const int* in_sizes, int n_in,
                              void* d_out, int out_size, void* d_ws, size_t ws_size,
                              hipStream_t stream) {
  const float* x     = (const float*)d_in[0];
  const float* ea    = (const float*)d_in[1];
  const float* gamma = (const float*)d_in[2];
  const float* beta  = (const float*)d_in[3];
  const float* w1    = (const float*)d_in[4];
  const float* b1    = (const float*)d_in[5];
  const float* w2    = (const float*)d_in[6];
  const float* b2    = (const float*)d_in[7];
  const float* root  = (const float*)d_in[8];
  const float* bias  = (const float*)d_in[9];
  const int*   ei    = (const int*)d_in[10];
  float* out = (float*)d_out;

  char* p = (char*)d_ws;
  auto carve = [&](size_t bytes) {
    char* q = p;
    p += (bytes + 255) & ~(size_t)255;
    return q;
  };
  float* h            = (float*)carve(sizeof(float) * NS * DD);
  unsigned short* h16 = (unsigned short*)carve(sizeof(short) * NS * DD);
  unsigned short* w2e = (unsigned short*)carve(sizeof(short) * (size_t)DD * BPAD);
  unsigned short* u16 = (unsigned short*)carve(sizeof(short) * (size_t)EE * HH);
  // contiguous zero-region: agg | cntdst (memset BEFORE k_prep — r13 lesson)
  char* z0 = p;
  float* agg          = (float*)carve(sizeof(float) * NS * DD);
  int* cntdst         = (int*)carve(sizeof(int) * NS);
  size_t zlen = (size_t)(p - z0);

  (void)hipMemsetAsync(z0, 0, zlen, stream);
  k_prep<<<dim3(TBLK + 1 + PBLK + UB), dim3(256), 0, stream>>>(
      x, gamma, beta, h, h16, ea, w2, w2e, w1, b1, u16, b2, ei, cntdst);
  k_msgd<<<dim3((EE + 127) / 128, 4), dim3(256), 0, stream>>>(
      u16, h16, w2e, ei, agg);
  k_final<<<dim3((NS + 31) / 32), dim3(256), 0, stream>>>(x, h, root, bias, agg,
                                                          cntdst, out);
}